// Round 1
// baseline (52.260 us; speedup 1.0000x reference)
//
#include <hip/hip_runtime.h>

// Sigma = R * diag(exp(s))^2 * R^T per Gaussian.
// Inputs: quats_raw (N,4) fp32, scales_raw (N,3) fp32. Output: (N,3,3) fp32.
// Memory-bound: 256 MB total traffic -> ~41 us roofline at 6.3 TB/s.

__global__ __launch_bounds__(256) void gaussian_sigma_kernel(
    const float4* __restrict__ quats,
    const float* __restrict__ scales,
    float* __restrict__ out,
    int n)
{
    int i = blockIdx.x * blockDim.x + threadIdx.x;
    if (i >= n) return;

    float4 q = quats[i];  // (w, x, y, z)
    float inv = rsqrtf(q.x * q.x + q.y * q.y + q.z * q.z + q.w * q.w);
    float w = q.x * inv, x = q.y * inv, y = q.z * inv, z = q.w * inv;

    float s0 = __expf(scales[3 * (size_t)i + 0]);
    float s1 = __expf(scales[3 * (size_t)i + 1]);
    float s2 = __expf(scales[3 * (size_t)i + 2]);

    float xx = x * x, yy = y * y, zz = z * z;
    float xy = x * y, xz = x * z, yz = y * z;
    float wx = w * x, wy = w * y, wz = w * z;

    float R00 = 1.f - 2.f * (yy + zz), R01 = 2.f * (xy - wz), R02 = 2.f * (xz + wy);
    float R10 = 2.f * (xy + wz), R11 = 1.f - 2.f * (xx + zz), R12 = 2.f * (yz - wx);
    float R20 = 2.f * (xz - wy), R21 = 2.f * (yz + wx), R22 = 1.f - 2.f * (xx + yy);

    // M = R @ diag(s): scale columns
    float M00 = R00 * s0, M01 = R01 * s1, M02 = R02 * s2;
    float M10 = R10 * s0, M11 = R11 * s1, M12 = R12 * s2;
    float M20 = R20 * s0, M21 = R21 * s1, M22 = R22 * s2;

    // Sigma = M @ M^T (symmetric)
    float S00 = M00 * M00 + M01 * M01 + M02 * M02;
    float S01 = M00 * M10 + M01 * M11 + M02 * M12;
    float S02 = M00 * M20 + M01 * M21 + M02 * M22;
    float S11 = M10 * M10 + M11 * M11 + M12 * M12;
    float S12 = M10 * M20 + M11 * M21 + M12 * M22;
    float S22 = M20 * M20 + M21 * M21 + M22 * M22;

    float* o = out + (size_t)i * 9;
    o[0] = S00; o[1] = S01; o[2] = S02;
    o[3] = S01; o[4] = S11; o[5] = S12;
    o[6] = S02; o[7] = S12; o[8] = S22;
}

extern "C" void kernel_launch(void* const* d_in, const int* in_sizes, int n_in,
                              void* d_out, int out_size, void* d_ws, size_t ws_size,
                              hipStream_t stream) {
    const float4* quats = (const float4*)d_in[0];
    const float* scales = (const float*)d_in[1];
    float* out = (float*)d_out;
    int n = in_sizes[0] / 4;  // quats_raw is (N,4)

    int block = 256;
    int grid = (n + block - 1) / block;
    gaussian_sigma_kernel<<<grid, block, 0, stream>>>(quats, scales, out, n);
}